// Round 7
// baseline (126.637 us; speedup 1.0000x reference)
//
#include <hip/hip_runtime.h>

// Problem constants
static constexpr int NQ    = 12;
static constexpr int DEPTH = 4;
static constexpr int LAT   = 512;
static constexpr int FAST  = DEPTH * NQ;   // 48
static constexpr float DECAY = 0.9f;

using v2f = __attribute__((ext_vector_type(2))) float;

// r21 KEY CHANGE: two-kernel split. r14-r20 all fused the angle computation
// (latent=tanh(x@W_enc^T); delta=latent@W_upd^T) into every circuit wave:
// each wave streamed ~120KB of weights privately and ran a 512-deep SERIAL
// dot chain per lane -- ~half of wave lifetime, with zero batch reuse.
// Doubling waves (r15/r20) doubled that work -> slower, which is why no
// circuit rewrite moved total time. The GEMM work is only ~126 MFLOP:
//   kernel 1 (fwp_angles): tiled batch GEMM -> angles -> (cos,sin) halfangle
//     table in d_ws. 512 blocks x 256 thr, 4 elem/block, latents in LDS,
//     4-way dot partials. W_upd stays L2-resident (96KB shared).
//   kernel 2 (fwp_circuit): r19-verified circuit verbatim (v2f-packed A/B,
//     sigma = G6 reg-rename + 2-index bperm pull, permlane32/16 sum-form
//     wires 6/7, DPP wires 8..11, packed register butterflies 0..5),
//     Phase A/B deleted; reads the cs table (384B/elem, coalesced).
// Same stream => ordered; no sync APIs => graph-capture safe.

__device__ __forceinline__ constexpr int G6(int x){ return (x ^ (x >> 1)) & 63; }

__device__ __forceinline__ float bperm(int idx, float v){
    return __int_as_float(__builtin_amdgcn_ds_bpermute(idx, __float_as_int(v)));
}
template<int CTRL>
__device__ __forceinline__ float dppf(float x){
    return __int_as_float(__builtin_amdgcn_mov_dpp(__float_as_int(x), CTRL, 0xF, 0xF, false));
}
template<int CTRL>
__device__ __forceinline__ v2f dpp2(v2f v){ return (v2f){dppf<CTRL>(v.x), dppf<CTRL>(v.y)}; }

// x[l] + x[l^32]  (direction-proof sum form, r19-verified)
__device__ __forceinline__ float xsum32(float x){
    float a = x, b = x;
    asm("v_permlane32_swap_b32 %0, %1" : "+v"(a), "+v"(b));
    return a + b;
}
// x[l] + x[l^16]  (r19-verified)
__device__ __forceinline__ float xsum16(float x){
    float a = x, b = x;
    asm("v_permlane16_swap_b32 %0, %1" : "+v"(a), "+v"(b));
    return a + b;
}

// packed register butterfly, wire stride S (amp bit), (A,B) in v2f
template<int S>
__device__ __forceinline__ void rw(v2f (&u)[64], v2f cc, v2f ss){
    #pragma unroll
    for (int r = 0; r < 64; r++){
        if (!(r & S)){
            v2f a = u[r], b = u[r | S];
            u[r]     = cc * a - ss * b;
            u[r | S] = ss * a + cc * b;
        }
    }
}

// ======================= kernel 1: angles ==================================
__global__ __launch_bounds__(256, 1)
void fwp_angles(const float* __restrict__ x_t,
                const float* __restrict__ fast_prev,
                const float* __restrict__ W_enc,
                const float* __restrict__ b_enc,
                const float* __restrict__ W_upd,
                const float* __restrict__ b_upd,
                float* __restrict__ out_fast,
                float2* __restrict__ cs_out) {
    const int t  = threadIdx.x;
    const int e0 = blockIdx.x * 4;                 // 4 elements per block

    __shared__ __align__(16) float lat[4][LAT];    // 8 KB
    __shared__ float xs[4 * NQ];                   // 192 B

    if (t < 4 * NQ) xs[t] = x_t[e0 * NQ + t];
    __syncthreads();

    // ---- latent: ee = t>>6 (64 threads/elem), 8 latents per thread ----
    {
        const int ee = t >> 6;
        float xr[NQ];
        #pragma unroll
        for (int m = 0; m < NQ; m++) xr[m] = xs[ee * NQ + m];
        #pragma unroll
        for (int k = 0; k < 8; k++) {
            const int j = (t & 63) | (k << 6);
            const float4* wr = (const float4*)(W_enc + j * NQ);
            float4 a0 = wr[0], a1 = wr[1], a2 = wr[2];
            float s = b_enc[j]
                + a0.x * xr[0] + a0.y * xr[1] + a0.z * xr[2]  + a0.w * xr[3]
                + a1.x * xr[4] + a1.y * xr[5] + a1.z * xr[6]  + a1.w * xr[7]
                + a2.x * xr[8] + a2.y * xr[9] + a2.z * xr[10] + a2.w * xr[11];
            lat[ee][j] = tanhf(s);
        }
    }
    __syncthreads();

    // ---- delta: 4*48 = 192 outputs, one per thread (t < 192) ----
    if (t < 4 * FAST) {
        const int ee = t / FAST;
        const int w  = t - ee * FAST;
        const float4* wr = (const float4*)(W_upd + w * LAT);
        const float4* la = (const float4*)(&lat[ee][0]);
        float s0 = 0.f, s1 = 0.f, s2 = 0.f, s3 = 0.f;   // break serial chain
        #pragma unroll 8
        for (int j = 0; j < LAT / 4; j += 4) {
            float4 w0 = wr[j],     l0 = la[j];
            float4 w1 = wr[j + 1], l1 = la[j + 1];
            float4 w2 = wr[j + 2], l2 = la[j + 2];
            float4 w3 = wr[j + 3], l3 = la[j + 3];
            s0 += w0.x * l0.x + w0.y * l0.y + w0.z * l0.z + w0.w * l0.w;
            s1 += w1.x * l1.x + w1.y * l1.y + w1.z * l1.z + w1.w * l1.w;
            s2 += w2.x * l2.x + w2.y * l2.y + w2.z * l2.z + w2.w * l2.w;
            s3 += w3.x * l3.x + w3.y * l3.y + w3.z * l3.z + w3.w * l3.w;
        }
        const int e   = e0 + ee;
        const int off = e * FAST + w;
        float ang = DECAY * fast_prev[off] + (b_upd[w] + ((s0 + s1) + (s2 + s3)));
        out_fast[off] = ang;
        float h = 0.5f * ang;
        cs_out[off] = (float2){__cosf(h), __sinf(h)};
    }
}

// ======================= kernel 2: circuit =================================
__global__ __launch_bounds__(64, 1)
void fwp_circuit(const float* __restrict__ x_t,
                 const float2* __restrict__ cs_in,
                 const float* __restrict__ W_ro,
                 const float* __restrict__ b_ro,
                 float* __restrict__ out_y) {
    const int lane = threadIdx.x;          // block = one wave
    const int eA   = 2 * blockIdx.x;
    const int eB   = eA + 1;

    __shared__ __align__(8) v2f CC[FAST], SS[FAST];   // zipped (A,B) halfangle cos/sin

    // ---- angles from kernel-1 table (coalesced float2) ----
    if (lane < FAST) {
        float2 a = cs_in[eA * FAST + lane];
        float2 b = cs_in[eB * FAST + lane];
        CC[lane] = (v2f){a.x, b.x};
        SS[lane] = (v2f){a.y, b.y};
    }

    // ---- x rows (wave-uniform scalar loads, verified r7) ----
    float xaA[NQ], xaB[NQ];
    #pragma unroll
    for (int k = 0; k < NQ; k++) {
        xaA[k] = x_t[eA * NQ + k];
        xaB[k] = x_t[eB * NQ + k];
    }

    // ---- packed product state: u[h] = (ampA, ampB); reg h = wires 0..5,
    //      lane l = wires 6..11  [r18/r19-verified] ----
    v2f u[64];
    {
        v2f g0[NQ], g1[NQ];
        #pragma unroll
        for (int w = 0; w < NQ; w++) {
            float hA = 0.5f * xaA[w], hB = 0.5f * xaB[w];
            float cA = __cosf(hA), sA = __sinf(hA);
            float cB = __cosf(hB), sB = __sinf(hB);
            const float K = 0.70710678118654752f;
            g0[w] = (v2f){(cA - sA) * K, (cB - sB) * K};
            g1[w] = (v2f){(cA + sA) * K, (cB + sB) * K};
        }
        v2f L = (v2f){1.0f, 1.0f};
        #pragma unroll
        for (int w = 6; w < NQ; w++)
            L *= ((lane >> (11 - w)) & 1) ? g1[w] : g0[w];
        u[0] = L;
        #pragma unroll
        for (int w = 0; w < 6; w++) {
            const int S = 32 >> w;
            #pragma unroll
            for (int r = 0; r < 64; r += 2 * S) {
                u[r + S] = u[r] * g1[w];
                u[r]     = u[r] * g0[w];
            }
        }
    }

    // sigma lane-pull index vectors (bytes) [r18/r19-verified]
    const int idxA = G6(lane) * 4;           // h0 = 0
    const int idxB = idxA ^ 128;             // h0 = 1  (^32 lanes)

    #define SIG1(h, src) { const int idx_ = ((h) & 1) ? idxB : idxA; \
        u[h] = (v2f){ bperm(idx_, (src).x), bperm(idx_, (src).y) }; }

    // ---- 4 layers [r19-verified circuit] ----
    #pragma unroll 1
    for (int layer = 0; layer < DEPTH; layer++) {
        v2f cc[NQ], ss[NQ];
        #pragma unroll
        for (int w = 0; w < NQ; w++) { cc[w] = CC[layer * NQ + w]; ss[w] = SS[layer * NQ + w]; }

        // -------- sigma: in-place along G6 register cycles --------
        SIG1(0, u[0]);  SIG1(1, u[1]);
        { v2f t = u[2]; SIG1(2, u[3]); SIG1(3, t); }
        { v2f t = u[4]; SIG1(4, u[6]);  SIG1(6, u[5]);  SIG1(5, u[7]);  SIG1(7, t); }
        { v2f t = u[8]; SIG1(8, u[12]); SIG1(12, u[10]); SIG1(10, u[15]); SIG1(15, t); }
        { v2f t = u[9]; SIG1(9, u[13]); SIG1(13, u[11]); SIG1(11, u[14]); SIG1(14, t); }
        { v2f t = u[16]; SIG1(16, u[24]); SIG1(24, u[20]); SIG1(20, u[30]); SIG1(30, u[17]);
                         SIG1(17, u[25]); SIG1(25, u[21]); SIG1(21, u[31]); SIG1(31, t); }
        { v2f t = u[18]; SIG1(18, u[27]); SIG1(27, u[22]); SIG1(22, u[29]); SIG1(29, u[19]);
                         SIG1(19, u[26]); SIG1(26, u[23]); SIG1(23, u[28]); SIG1(28, t); }
        { v2f t = u[32]; SIG1(32, u[48]); SIG1(48, u[40]); SIG1(40, u[60]); SIG1(60, u[34]);
                         SIG1(34, u[51]); SIG1(51, u[42]); SIG1(42, u[63]); SIG1(63, t); }
        { v2f t = u[33]; SIG1(33, u[49]); SIG1(49, u[41]); SIG1(41, u[61]); SIG1(61, u[35]);
                         SIG1(35, u[50]); SIG1(50, u[43]); SIG1(43, u[62]); SIG1(62, t); }
        { v2f t = u[36]; SIG1(36, u[54]); SIG1(54, u[45]); SIG1(45, u[59]); SIG1(59, u[38]);
                         SIG1(38, u[53]); SIG1(53, u[47]); SIG1(47, u[56]); SIG1(56, t); }
        { v2f t = u[37]; SIG1(37, u[55]); SIG1(55, u[44]); SIG1(44, u[58]); SIG1(58, u[39]);
                         SIG1(39, u[52]); SIG1(52, u[46]); SIG1(46, u[57]); SIG1(57, t); }

        // -------- wire6: xor32 via permlane32 sum form --------
        {
            v2f sv = (lane & 32) ? ss[6] : -ss[6];
            v2f cm = cc[6] - sv;
            #pragma unroll
            for (int h = 0; h < 64; h++) {
                v2f s2 = (v2f){ xsum32(u[h].x), xsum32(u[h].y) };
                u[h] = cm * u[h] + sv * s2;
            }
        }
        // -------- wire7: xor16 via permlane16 sum form --------
        {
            v2f sv = (lane & 16) ? ss[7] : -ss[7];
            v2f cm = cc[7] - sv;
            #pragma unroll
            for (int h = 0; h < 64; h++) {
                v2f s2 = (v2f){ xsum16(u[h].x), xsum16(u[h].y) };
                u[h] = cm * u[h] + sv * s2;
            }
        }
        // -------- wire8: xor8 via DPP row_ror:8 --------
        {
            v2f sv = (lane & 8) ? ss[8] : -ss[8];
            #pragma unroll
            for (int h = 0; h < 64; h++) {
                v2f p = dpp2<0x128>(u[h]);
                u[h] = cc[8] * u[h] + sv * p;
            }
        }
        // -------- wire9: xor4 = half_mirror o quad_perm[3,2,1,0] --------
        {
            v2f sv = (lane & 4) ? ss[9] : -ss[9];
            #pragma unroll
            for (int h = 0; h < 64; h++) {
                v2f p = dpp2<0x141>(dpp2<0x1B>(u[h]));
                u[h] = cc[9] * u[h] + sv * p;
            }
        }
        // -------- wire10: xor2 quad_perm[2,3,0,1] --------
        {
            v2f sv = (lane & 2) ? ss[10] : -ss[10];
            #pragma unroll
            for (int h = 0; h < 64; h++) {
                v2f p = dpp2<0x4E>(u[h]);
                u[h] = cc[10] * u[h] + sv * p;
            }
        }
        // -------- wire11: xor1 quad_perm[1,0,3,2] --------
        {
            v2f sv = (lane & 1) ? ss[11] : -ss[11];
            #pragma unroll
            for (int h = 0; h < 64; h++) {
                v2f p = dpp2<0xB1>(u[h]);
                u[h] = cc[11] * u[h] + sv * p;
            }
        }
        // -------- wires 0..5: packed register butterflies --------
        rw<32>(u, cc[0], ss[0]);
        rw<16>(u, cc[1], ss[1]);
        rw<8> (u, cc[2], ss[2]);
        rw<4> (u, cc[3], ss[3]);
        rw<2> (u, cc[4], ss[4]);
        rw<1> (u, cc[5], ss[5]);
    }
    #undef SIG1

    // ---- Z expectations folded into readout [r18/r19-verified mapping] ----
    float wro[NQ];
    #pragma unroll
    for (int w = 0; w < NQ; w++) wro[w] = W_ro[w];
    float sl = 0.0f;
    #pragma unroll
    for (int w = 6; w < NQ; w++)
        sl += ((lane >> (11 - w)) & 1) ? -wro[w] : wro[w];

    v2f tot = (v2f){0.0f, 0.0f};
    v2f pw[6];
    #pragma unroll
    for (int k = 0; k < 6; k++) pw[k] = (v2f){0.0f, 0.0f};
    #pragma unroll
    for (int r = 0; r < 64; r++) {
        v2f p = u[r] * u[r];
        tot += p;
        pw[0] += (r & 32) ? -p : p;   // wire0 (reg bit5)
        pw[1] += (r & 16) ? -p : p;
        pw[2] += (r & 8)  ? -p : p;
        pw[3] += (r & 4)  ? -p : p;
        pw[4] += (r & 2)  ? -p : p;
        pw[5] += (r & 1)  ? -p : p;   // wire5 (reg bit0)
    }
    v2f y2 = (v2f){sl, sl} * tot;
    #pragma unroll
    for (int k = 0; k < 6; k++) y2 += (v2f){wro[k], wro[k]} * pw[k];
    float yA = y2.x, yB = y2.y;
    #pragma unroll
    for (int m = 32; m >= 1; m >>= 1) {
        yA += __shfl_xor(yA, m, 64);
        yB += __shfl_xor(yB, m, 64);
    }
    if (lane == 0) {
        float br = b_ro[0];
        out_y[eA] = yA + br;
        out_y[eB] = yB + br;
    }
}

extern "C" void kernel_launch(void* const* d_in, const int* in_sizes, int n_in,
                              void* d_out, int out_size, void* d_ws, size_t ws_size,
                              hipStream_t stream) {
    const float* x_t       = (const float*)d_in[0];
    const float* fast_prev = (const float*)d_in[1];
    const float* W_enc     = (const float*)d_in[2];
    const float* b_enc     = (const float*)d_in[3];
    const float* W_upd     = (const float*)d_in[4];
    const float* b_upd     = (const float*)d_in[5];
    const float* W_ro      = (const float*)d_in[6];
    const float* b_ro      = (const float*)d_in[7];
    float* out = (float*)d_out;
    float2* cs_tab = (float2*)d_ws;    // 2048*48*8 = 786432 B

    // kernel 1: angles (512 blocks x 256 thr, 4 elem/block)
    fwp_angles<<<512, 256, 0, stream>>>(x_t, fast_prev, W_enc, b_enc,
                                        W_upd, b_upd,
                                        out + 2048 /*fast_next*/, cs_tab);
    // kernel 2: circuit (1024 blocks x 1 wave, 2 elem/wave), stream-ordered
    fwp_circuit<<<1024, 64, 0, stream>>>(x_t, cs_tab, W_ro, b_ro, out /*y*/);
}

// Round 8
// 112.348 us; speedup vs baseline: 1.1272x; 1.1272x over previous
//
#include <hip/hip_runtime.h>

// Problem constants
static constexpr int NQ    = 12;
static constexpr int DEPTH = 4;
static constexpr int LAT   = 512;
static constexpr int FAST  = DEPTH * NQ;   // 48
static constexpr float DECAY = 0.9f;
static constexpr int P     = 68;           // row pitch (floats): 272 B, 16B-aligned

using v2f = __attribute__((ext_vector_type(2))) float;

// r22 = r14 (best proven: 48us dispatch / 106us bench) + three surgical cuts:
//  1. init_state hoisted before Phase A/B: its trig overlaps the weight-load
//     latency instead of running after it.
//  2. Phase B uses 4 partial sums (breaks the 128-deep serial FMA chain;
//     reassociation validated by r21's passing absmax with the same split).
//  3. Final pass-2 round-trip eliminated: after last layer's pass1+ry6,
//     wires 6..11 are applied as LANE wires (permlane32/16 sum-form +
//     DPP xor8/4/2/1, r19/r20 HW-verified) and the readout runs in T
//     orientation (r18 HW-verified mapping). -160 DS ops, -2 drain walls.
// Rationale (r15-r21 evidence): every macro-restructure lands in a 48-81us
// stall envelope; r14 was never beaten. Bench = dispatch + ~58us fixed, so
// only dispatch time matters. Consolidate + shave.

template<int S, int B>
__device__ __forceinline__ void bfly_half(float (&v)[64], float c, float s) {
    v2f c2 = {c, c}, s2 = {s, s};
    #pragma unroll
    for (int r0 = B; r0 < B + 32; r0 += 2) {
        if ((r0 & S) == 0) {
            v2f a = {v[r0],     v[r0 + 1]};
            v2f b = {v[r0 + S], v[r0 + S + 1]};
            v2f na = c2 * a - s2 * b;
            v2f nb = s2 * a + c2 * b;
            v[r0]     = na.x;  v[r0 + 1]     = na.y;
            v[r0 + S] = nb.x;  v[r0 + S + 1] = nb.y;
        }
    }
}

template<int B>
__device__ __forceinline__ void bfly1_half(float (&v)[64], float c, float s) {
    v2f cs = {c, s}, nsc = {-s, c};
    #pragma unroll
    for (int r0 = B; r0 < B + 32; r0 += 2) {
        float a = v[r0], b = v[r0 + 1];
        v2f aa = {a, a}, bb = {b, b};
        v2f res = cs * aa + nsc * bb;   // (c*a - s*b, s*a + c*b)
        v[r0]     = res.x;
        v[r0 + 1] = res.y;
    }
}

template<int B>
__device__ __forceinline__ void ry5_half(float (&v)[64], const v2f* cs) {
    bfly_half<16, B>(v, cs[0].x, cs[0].y);
    bfly_half<8,  B>(v, cs[1].x, cs[1].y);
    bfly_half<4,  B>(v, cs[2].x, cs[2].y);
    bfly_half<2,  B>(v, cs[3].x, cs[3].y);
    bfly1_half<B>(v, cs[4].x, cs[4].y);
}

__device__ __forceinline__ void bfly32(float (&v)[64], float c, float s) {
    v2f c2 = {c, c}, s2 = {s, s};
    #pragma unroll
    for (int r0 = 0; r0 < 32; r0 += 2) {
        v2f a = {v[r0],      v[r0 + 1]};
        v2f b = {v[r0 + 32], v[r0 + 33]};
        v2f na = c2 * a - s2 * b;
        v2f nb = s2 * a + c2 * b;
        v[r0]      = na.x;  v[r0 + 1]  = na.y;
        v[r0 + 32] = nb.x;  v[r0 + 33] = nb.y;
    }
}

// full 6-wire butterfly block for one orientation (wires cs[0..5], cs[0]=stride32)
__device__ __forceinline__ void ry6(float (&v)[64], const v2f* cs) {
    ry5_half<0>(v, cs + 1);
    ry5_half<32>(v, cs + 1);
    bfly32(v, cs[0].x, cs[0].y);   // stride-32 wire last (commutes)
}

// pass-1 pieces (verified r13)
__device__ __forceinline__ void p1w(const float (&v)[64], float* X, int lane) {
    #pragma unroll
    for (int k = 0; k < 16; k++)
        *(float4*)&X[lane * P + 4 * k] =
            (float4){v[4 * k], v[4 * k + 1], v[4 * k + 2], v[4 * k + 3]};
}
__device__ __forceinline__ void p1r(float (&v)[64], const float* X, int A0, int A1) {
    #pragma unroll
    for (int r = 0; r < 64; r++) {
        const int g = r ^ (r >> 1);                 // compile-time imm offset
        v[r] = X[g * P + ((r & 1) ? A1 : A0)];
    }
}
// pass-2 pieces (verified r13)
__device__ __forceinline__ void p2w(const float (&v)[64], float* X, int lane) {
    #pragma unroll
    for (int q = 0; q < 64; q++) X[q * P + lane] = v[q];   // addr = lane*4 + imm
}
__device__ __forceinline__ void p2r(float (&v)[64], const float* X, int lane) {
    #pragma unroll
    for (int k = 0; k < 16; k++) {
        float4 t = *(const float4*)&X[lane * P + 4 * k];
        v[4 * k]     = t.x;  v[4 * k + 1] = t.y;
        v[4 * k + 2] = t.z;  v[4 * k + 3] = t.w;
    }
}

// lane exchanges (r19/r20 HW-verified)
template<int CTRL>
__device__ __forceinline__ float dppf(float x){
    return __int_as_float(__builtin_amdgcn_mov_dpp(__float_as_int(x), CTRL, 0xF, 0xF, false));
}
__device__ __forceinline__ float xsum32(float x){          // x + x[lane^32]
    float a = x, b = x;
    asm("v_permlane32_swap_b32 %0, %1" : "+v"(a), "+v"(b));
    return a + b;
}
__device__ __forceinline__ float xsum16(float x){          // x + x[lane^16]
    float a = x, b = x;
    asm("v_permlane16_swap_b32 %0, %1" : "+v"(a), "+v"(b));
    return a + b;
}

// closed-form product state from the 12 initial RYs (verified r2-r13)
__device__ __forceinline__ void init_state(float (&v)[64], const float (&xa)[NQ], int lane) {
    float g0[NQ], g1[NQ];
    #pragma unroll
    for (int w = 0; w < NQ; w++) {
        float hh = 0.5f * xa[w];
        float c = __cosf(hh), s = __sinf(hh);
        g0[w] = (c - s) * 0.70710678118654752f;
        g1[w] = (c + s) * 0.70710678118654752f;
    }
    float L = 1.0f;
    #pragma unroll
    for (int w = 0; w < 6; w++)
        L *= ((lane >> (5 - w)) & 1) ? g1[w] : g0[w];
    v[0] = L;
    #pragma unroll
    for (int w = 6; w < NQ; w++) {
        const int S = 1 << (11 - w);
        #pragma unroll
        for (int r = 0; r < 64; r += 2 * S) {
            v[r + S] = v[r] * g1[w];
            v[r]     = v[r] * g0[w];
        }
    }
}

__global__ __launch_bounds__(64, 1)
void fwp_kernel(const float* __restrict__ x_t,
                const float* __restrict__ fast_prev,
                const float* __restrict__ W_enc,
                const float* __restrict__ b_enc,
                const float* __restrict__ W_upd,
                const float* __restrict__ b_upd,
                const float* __restrict__ W_ro,
                const float* __restrict__ b_ro,
                float* __restrict__ out_y,
                float* __restrict__ out_fast) {
    const int lane = threadIdx.x;          // block = one wave
    const int eA   = 2 * blockIdx.x;
    const int eB   = eA + 1;

    __shared__ __align__(16) float XA[64 * P];   // 17408 B
    __shared__ __align__(16) float XB[64 * P];   // 17408 B
    __shared__ __align__(8)  v2f   csA[FAST], csB[FAST];

    float* latA = XA;   // latents carved from circuit buffers (dead later)
    float* latB = XB;

    // ---- x rows (wave-uniform scalar loads, verified r7) ----
    float xaA[NQ], xaB[NQ];
    #pragma unroll
    for (int k = 0; k < NQ; k++) {
        xaA[k] = x_t[eA * NQ + k];
        xaB[k] = x_t[eB * NQ + k];
    }

    // ---- product states FIRST: trig overlaps Phase A/B load latency ----
    float vA[64], vB[64];
    init_state(vA, xaA, lane);
    init_state(vB, xaB, lane);

    // ---- Phase A: lane owns latents j = 8*lane..8*lane+7 (verified r13) ----
    {
        const float4* we = (const float4*)(W_enc + lane * 8 * NQ);  // 8 rows, 384 B
        float4 be0 = *(const float4*)&b_enc[8 * lane];
        float4 be1 = *(const float4*)&b_enc[8 * lane + 4];
        float be[8] = {be0.x, be0.y, be0.z, be0.w, be1.x, be1.y, be1.z, be1.w};
        float lA[8], lB[8];
        #pragma unroll
        for (int t = 0; t < 8; t++) {
            float4 a0 = we[3 * t], a1 = we[3 * t + 1], a2 = we[3 * t + 2];
            float sA = be[t]
                + a0.x * xaA[0] + a0.y * xaA[1] + a0.z * xaA[2]  + a0.w * xaA[3]
                + a1.x * xaA[4] + a1.y * xaA[5] + a1.z * xaA[6]  + a1.w * xaA[7]
                + a2.x * xaA[8] + a2.y * xaA[9] + a2.z * xaA[10] + a2.w * xaA[11];
            float sB = be[t]
                + a0.x * xaB[0] + a0.y * xaB[1] + a0.z * xaB[2]  + a0.w * xaB[3]
                + a1.x * xaB[4] + a1.y * xaB[5] + a1.z * xaB[6]  + a1.w * xaB[7]
                + a2.x * xaB[8] + a2.y * xaB[9] + a2.z * xaB[10] + a2.w * xaB[11];
            lA[t] = tanhf(sA);
            lB[t] = tanhf(sB);
        }
        *(float4*)&latA[8 * lane]     = (float4){lA[0], lA[1], lA[2], lA[3]};
        *(float4*)&latA[8 * lane + 4] = (float4){lA[4], lA[5], lA[6], lA[7]};
        *(float4*)&latB[8 * lane]     = (float4){lB[0], lB[1], lB[2], lB[3]};
        *(float4*)&latB[8 * lane + 4] = (float4){lB[4], lB[5], lB[6], lB[7]};
    }

    // ---- Phase B: 48 angles per element; 4-way partial sums ----
    if (lane < FAST) {
        const float4* wr = (const float4*)(W_upd + lane * LAT);
        const float4* la = (const float4*)(latA);
        const float4* lb = (const float4*)(latB);
        float a0s = 0.f, a1s = 0.f, a2s = 0.f, a3s = 0.f;
        float b0s = 0.f, b1s = 0.f, b2s = 0.f, b3s = 0.f;
        #pragma unroll 4
        for (int j = 0; j < LAT / 4; j += 4) {
            float4 w0 = wr[j],     w1 = wr[j + 1], w2 = wr[j + 2], w3 = wr[j + 3];
            float4 p0 = la[j],     p1 = la[j + 1], p2 = la[j + 2], p3 = la[j + 3];
            float4 q0 = lb[j],     q1 = lb[j + 1], q2 = lb[j + 2], q3 = lb[j + 3];
            a0s += w0.x * p0.x + w0.y * p0.y + w0.z * p0.z + w0.w * p0.w;
            a1s += w1.x * p1.x + w1.y * p1.y + w1.z * p1.z + w1.w * p1.w;
            a2s += w2.x * p2.x + w2.y * p2.y + w2.z * p2.z + w2.w * p2.w;
            a3s += w3.x * p3.x + w3.y * p3.y + w3.z * p3.z + w3.w * p3.w;
            b0s += w0.x * q0.x + w0.y * q0.y + w0.z * q0.z + w0.w * q0.w;
            b1s += w1.x * q1.x + w1.y * q1.y + w1.z * q1.z + w1.w * q1.w;
            b2s += w2.x * q2.x + w2.y * q2.y + w2.z * q2.z + w2.w * q2.w;
            b3s += w3.x * q3.x + w3.y * q3.y + w3.z * q3.z + w3.w * q3.w;
        }
        float base = b_upd[lane];
        float sA = base + ((a0s + a1s) + (a2s + a3s));
        float sB = base + ((b0s + b1s) + (b2s + b3s));
        float angA = DECAY * fast_prev[eA * FAST + lane] + sA;
        float angB = DECAY * fast_prev[eB * FAST + lane] + sB;
        out_fast[eA * FAST + lane] = angA;
        out_fast[eB * FAST + lane] = angB;
        csA[lane] = (v2f){__cosf(0.5f * angA), __sinf(0.5f * angA)};
        csB[lane] = (v2f){__cosf(0.5f * angB), __sinf(0.5f * angB)};
    }

    const int A0 = ((lane ^ (lane >> 1)) & 31) | (lane & 32);
    const int A1 = A0 ^ 32;

    v2f caL[NQ], cbL[NQ];   // last-layer coefficients (kept for the tail)

    // ---- layers 0..2: r14's proven 2-pass structure ----
    #pragma unroll 1
    for (int layer = 0; layer < DEPTH - 1; layer++) {
        v2f ca[NQ], cb[NQ];
        #pragma unroll
        for (int w = 0; w < NQ; w++) {
            ca[w] = csA[layer * NQ + w];
            cb[w] = csB[layer * NQ + w];
        }

        // -------- pass 1 (sigma + L->T): fused DS bursts, then math --------
        p1w(vA, XA, lane);
        p1w(vB, XB, lane);
        p1r(vA, XA, A0, A1);
        p1r(vB, XB, A0, A1);     // outstanding while A's butterflies run
        ry6(vA, ca);             // waits lgkmcnt(15): most B-reads already done
        ry6(vB, cb);

        // -------- pass 2 (transpose back): fused DS bursts, then math --------
        p2w(vA, XA, lane);
        p2w(vB, XB, lane);
        p2r(vA, XA, lane);
        p2r(vB, XB, lane);
        ry6(vA, ca + 6);
        ry6(vB, cb + 6);
    }

    // ---- last layer: pass 1 + ry6, then wires 6..11 as LANE wires (no pass 2) ----
    {
        #pragma unroll
        for (int w = 0; w < NQ; w++) {
            caL[w] = csA[(DEPTH - 1) * NQ + w];
            cbL[w] = csB[(DEPTH - 1) * NQ + w];
        }
        p1w(vA, XA, lane);
        p1w(vB, XB, lane);
        p1r(vA, XA, A0, A1);
        p1r(vB, XB, A0, A1);
        ry6(vA, caL);            // wires 0..5 (reg-resident in T)
        ry6(vB, cbL);

        // T orientation: lane bit5 <-> wire6 ... lane bit0 <-> wire11.
        // All exchange forms HW-verified (r19/r20).
        // wire6: xor32 (permlane32 sum form)
        {
            float svA = (lane & 32) ? caL[6].y : -caL[6].y;
            float svB = (lane & 32) ? cbL[6].y : -cbL[6].y;
            float cmA = caL[6].x - svA, cmB = cbL[6].x - svB;
            #pragma unroll
            for (int h = 0; h < 64; h++) {
                vA[h] = __builtin_fmaf(cmA, vA[h], svA * xsum32(vA[h]));
                vB[h] = __builtin_fmaf(cmB, vB[h], svB * xsum32(vB[h]));
            }
        }
        // wire7: xor16 (permlane16 sum form)
        {
            float svA = (lane & 16) ? caL[7].y : -caL[7].y;
            float svB = (lane & 16) ? cbL[7].y : -cbL[7].y;
            float cmA = caL[7].x - svA, cmB = cbL[7].x - svB;
            #pragma unroll
            for (int h = 0; h < 64; h++) {
                vA[h] = __builtin_fmaf(cmA, vA[h], svA * xsum16(vA[h]));
                vB[h] = __builtin_fmaf(cmB, vB[h], svB * xsum16(vB[h]));
            }
        }
        // wire8: xor8 (DPP row_ror:8)
        {
            float svA = (lane & 8) ? caL[8].y : -caL[8].y;
            float svB = (lane & 8) ? cbL[8].y : -cbL[8].y;
            #pragma unroll
            for (int h = 0; h < 64; h++) {
                vA[h] = __builtin_fmaf(caL[8].x, vA[h], svA * dppf<0x128>(vA[h]));
                vB[h] = __builtin_fmaf(cbL[8].x, vB[h], svB * dppf<0x128>(vB[h]));
            }
        }
        // wire9: xor4 (half_mirror o quad_perm[3,2,1,0])
        {
            float svA = (lane & 4) ? caL[9].y : -caL[9].y;
            float svB = (lane & 4) ? cbL[9].y : -cbL[9].y;
            #pragma unroll
            for (int h = 0; h < 64; h++) {
                vA[h] = __builtin_fmaf(caL[9].x, vA[h], svA * dppf<0x141>(dppf<0x1B>(vA[h])));
                vB[h] = __builtin_fmaf(cbL[9].x, vB[h], svB * dppf<0x141>(dppf<0x1B>(vB[h])));
            }
        }
        // wire10: xor2 (quad_perm[2,3,0,1])
        {
            float svA = (lane & 2) ? caL[10].y : -caL[10].y;
            float svB = (lane & 2) ? cbL[10].y : -cbL[10].y;
            #pragma unroll
            for (int h = 0; h < 64; h++) {
                vA[h] = __builtin_fmaf(caL[10].x, vA[h], svA * dppf<0x4E>(vA[h]));
                vB[h] = __builtin_fmaf(cbL[10].x, vB[h], svB * dppf<0x4E>(vB[h]));
            }
        }
        // wire11: xor1 (quad_perm[1,0,3,2])
        {
            float svA = (lane & 1) ? caL[11].y : -caL[11].y;
            float svB = (lane & 1) ? cbL[11].y : -cbL[11].y;
            #pragma unroll
            for (int h = 0; h < 64; h++) {
                vA[h] = __builtin_fmaf(caL[11].x, vA[h], svA * dppf<0xB1>(vA[h]));
                vB[h] = __builtin_fmaf(cbL[11].x, vB[h], svB * dppf<0xB1>(vB[h]));
            }
        }
    }

    // ---- readout in T orientation (r18 HW-verified mapping) ----
    // lane bits = wires 6..11 (bit 11-w), reg bits = wires 0..5 (bit 5-k)
    float wro[NQ];
    #pragma unroll
    for (int w = 0; w < NQ; w++) wro[w] = W_ro[w];
    float sl = 0.0f;
    #pragma unroll
    for (int w = 6; w < NQ; w++)
        sl += ((lane >> (11 - w)) & 1) ? -wro[w] : wro[w];

    float totA = 0.0f, pwA[6] = {0,0,0,0,0,0};
    float totB = 0.0f, pwB[6] = {0,0,0,0,0,0};
    #pragma unroll
    for (int r = 0; r < 64; r++) {
        float pA = vA[r] * vA[r];
        float pB = vB[r] * vB[r];
        totA += pA;  totB += pB;
        pwA[0] += (r & 32) ? -pA : pA;  pwB[0] += (r & 32) ? -pB : pB;  // wire0
        pwA[1] += (r & 16) ? -pA : pA;  pwB[1] += (r & 16) ? -pB : pB;  // wire1
        pwA[2] += (r & 8)  ? -pA : pA;  pwB[2] += (r & 8)  ? -pB : pB;  // wire2
        pwA[3] += (r & 4)  ? -pA : pA;  pwB[3] += (r & 4)  ? -pB : pB;  // wire3
        pwA[4] += (r & 2)  ? -pA : pA;  pwB[4] += (r & 2)  ? -pB : pB;  // wire4
        pwA[5] += (r & 1)  ? -pA : pA;  pwB[5] += (r & 1)  ? -pB : pB;  // wire5
    }
    float yA = sl * totA, yB = sl * totB;
    #pragma unroll
    for (int k = 0; k < 6; k++) {
        yA += wro[k] * pwA[k];
        yB += wro[k] * pwB[k];
    }
    #pragma unroll
    for (int m = 32; m >= 1; m >>= 1) {
        yA += __shfl_xor(yA, m, 64);
        yB += __shfl_xor(yB, m, 64);
    }
    if (lane == 0) {
        float br = b_ro[0];
        out_y[eA] = yA + br;
        out_y[eB] = yB + br;
    }
}

extern "C" void kernel_launch(void* const* d_in, const int* in_sizes, int n_in,
                              void* d_out, int out_size, void* d_ws, size_t ws_size,
                              hipStream_t stream) {
    const float* x_t       = (const float*)d_in[0];
    const float* fast_prev = (const float*)d_in[1];
    const float* W_enc     = (const float*)d_in[2];
    const float* b_enc     = (const float*)d_in[3];
    const float* W_upd     = (const float*)d_in[4];
    const float* b_upd     = (const float*)d_in[5];
    const float* W_ro      = (const float*)d_in[6];
    const float* b_ro      = (const float*)d_in[7];
    float* out = (float*)d_out;

    // 1024 blocks x 1 wave, 2 batch elements per wave
    fwp_kernel<<<1024, 64, 0, stream>>>(x_t, fast_prev, W_enc, b_enc,
                                        W_upd, b_upd, W_ro, b_ro,
                                        out /*y*/, out + 2048 /*fast_next*/);
}